// Round 1
// baseline (2287.364 us; speedup 1.0000x reference)
//
#include <hip/hip_runtime.h>
#include <hip/hip_bf16.h>

#define BB 128
#define TT 25
#define VOCAB 10000
#define HIDD 512

typedef __hip_bfloat16 bf16;
typedef short bf16x8 __attribute__((ext_vector_type(8)));
typedef float f32x4 __attribute__((ext_vector_type(4)));

__device__ __forceinline__ float sigmoidf_(float x) { return 1.0f / (1.0f + __expf(-x)); }

__device__ __forceinline__ float4 f4_fma(float s, float4 w, float4 a) {
    a.x += s * w.x; a.y += s * w.y; a.z += s * w.z; a.w += s * w.w;
    return a;
}

__device__ __forceinline__ unsigned short f2bfu(float x) {
    bf16 h = __float2bfloat16(x);
    return *reinterpret_cast<unsigned short*>(&h);
}

// ---------------------------------------------------------------------
// h0 path (unchanged math; k_h0f now writes TRANSPOSED states)
// ---------------------------------------------------------------------
__device__ __forceinline__ float4 core128(const float* __restrict__ Wp,
                                          const float* __restrict__ arow)
{
    float4 acc = {0.f, 0.f, 0.f, 0.f};
    #pragma unroll 2
    for (int k = 0; k < 128; k += 8) {
        float4 w[8];
        #pragma unroll
        for (int j = 0; j < 8; ++j)
            w[j] = *(const float4*)(Wp + (size_t)(k + j) * 512);
        #pragma unroll
        for (int j = 0; j < 8; ++j)
            acc = f4_fma(arow[k + j], w[j], acc);
    }
    return acc;
}

#define PHASE_REDUCE(SVAR) \
    __syncthreads(); \
    float4 SVAR; \
    if (tid < 32) { \
        SVAR = red[tid]; \
        _Pragma("unroll") \
        for (int j = 1; j < 8; ++j) { \
            float4 p = red[tid + 32 * j]; \
            SVAR.x += p.x; SVAR.y += p.y; SVAR.z += p.z; SVAR.w += p.w; \
        } \
    }

// vgg[128,4096] @ W_in[4096,512], K split over 4 blocks (z). grid (8,64,4)
__global__ __launch_bounds__(256) void k_h0p(const float* __restrict__ A,
                                             const float* __restrict__ W,
                                             float* __restrict__ partial)
{
    __shared__ float As2[2][1032];
    __shared__ float4 red[256];
    const int tid = threadIdx.x;
    const int n4 = tid & 15, mi = (tid >> 4) & 1, kh = tid >> 5;
    const int m0 = blockIdx.y * 2, col0 = blockIdx.x * 64, kq = blockIdx.z;

    #pragma unroll
    for (int l = 0; l < 2; ++l) {
        int idx = tid + l * 256;
        int r = idx >> 8, c4 = (idx & 255) * 4;
        *(float4*)&As2[r][c4] =
            *(const float4*)&A[(size_t)(m0 + r) * 4096 + kq * 1024 + c4];
    }
    __syncthreads();
    red[tid] = core128(W + (size_t)(kq * 1024 + kh * 128) * 512 + col0 + n4 * 4,
                       &As2[mi][kh * 128]);
    PHASE_REDUCE(s)
    if (tid < 32) {
        int m = m0 + (tid >> 4), cc = col0 + (tid & 15) * 4;
        *(float4*)&partial[((size_t)kq * 128 + m) * 512 + cc] = s;
    }
}

// finalize: sum 4 partials + bias, tanh, write TRANSPOSED h0T/h1T [512][128]
__global__ void k_h0f(const float* __restrict__ partial,
                      const float* __restrict__ bias,
                      float* __restrict__ h0T1, float* __restrict__ h1T1)
{
    int i = blockIdx.x * 256 + threadIdx.x;   // float4 index over 128*512/4
    size_t e = (size_t)i * 4;
    int r = (int)(e >> 9), cc = (int)(e & 511);
    float4 s = *(const float4*)&partial[e];
    #pragma unroll
    for (int j = 1; j < 4; ++j) {
        float4 p = *(const float4*)&partial[(size_t)j * 128 * 512 + e];
        s.x += p.x; s.y += p.y; s.z += p.z; s.w += p.w;
    }
    float4 b4 = *(const float4*)&bias[cc];
    float4 o;
    o.x = tanhf(s.x + b4.x); o.y = tanhf(s.y + b4.y);
    o.z = tanhf(s.z + b4.z); o.w = tanhf(s.w + b4.w);
    h0T1[(size_t)(cc + 0) * 128 + r] = o.x;
    h0T1[(size_t)(cc + 1) * 128 + r] = o.y;
    h0T1[(size_t)(cc + 2) * 128 + r] = o.z;
    h0T1[(size_t)(cc + 3) * 128 + r] = o.w;
    h1T1[(size_t)(cc + 0) * 128 + r] = o.x;
    h1T1[(size_t)(cc + 1) * 128 + r] = o.y;
    h1T1[(size_t)(cc + 2) * 128 + r] = o.z;
    h1T1[(size_t)(cc + 3) * 128 + r] = o.w;
}

// ---------------------------------------------------------------------
// x pre-gather: emb[tok[r][t]] -> xT [512][128] (transposed)
// ---------------------------------------------------------------------
__device__ __forceinline__ void xgather_body(const int* __restrict__ toks,
                                             const float* __restrict__ emb,
                                             int t, float* __restrict__ dst, int j)
{
    __shared__ float T[8][516];
    const int tid = threadIdx.x;
    #pragma unroll
    for (int p = 0; p < 4; ++p) {
        int idx = tid + p * 256;               // 1024 float4s = 8 rows x 512
        int r = idx >> 7, c4 = (idx & 127) * 4;
        int tok = toks[(j * 8 + r) * TT + t];
        *(float4*)&T[r][c4] = *(const float4*)&emb[(size_t)tok * 512 + c4];
    }
    __syncthreads();
    #pragma unroll
    for (int p = 0; p < 2; ++p) {
        int k = tid + p * 256;
        float4 v0, v1;
        v0.x = T[0][k]; v0.y = T[1][k]; v0.z = T[2][k]; v0.w = T[3][k];
        v1.x = T[4][k]; v1.y = T[5][k]; v1.z = T[6][k]; v1.w = T[7][k];
        *(float4*)&dst[(size_t)k * 128 + j * 8]     = v0;
        *(float4*)&dst[(size_t)k * 128 + j * 8 + 4] = v1;
    }
}

__global__ __launch_bounds__(256) void k_xgather(const int* __restrict__ toks,
                                                 const float* __restrict__ emb,
                                                 int t, float* __restrict__ dst)
{
    xgather_body(toks, emb, t, dst, blockIdx.x);
}

// ---------------------------------------------------------------------
// Register-pipelined K-half accumulators. A is transposed [512][128].
// wsp points at &Ws[khalf_base*STRIDE + c]; indices j*STRIDE.
// 2-deep x 16-k software pipeline, all array indices compile-time.
// ---------------------------------------------------------------------
#define KB 16

__device__ __forceinline__ void acc_half4(const float* __restrict__ A,
                                          const float* __restrict__ wsp,
                                          int r0, float4& acc)
{
    float4 aA[KB], aB[KB];
    float  wA[KB], wB[KB];
    #pragma unroll
    for (int j = 0; j < KB; ++j) {
        aA[j] = *(const float4*)&A[(size_t)j * 128 + r0];
        wA[j] = wsp[j * 8];
    }
    #pragma unroll 1
    for (int k = KB; k < 512 - KB; k += 2 * KB) {
        #pragma unroll
        for (int j = 0; j < KB; ++j) {
            aB[j] = *(const float4*)&A[(size_t)(k + j) * 128 + r0];
            wB[j] = wsp[(k + j) * 8];
        }
        #pragma unroll
        for (int j = 0; j < KB; ++j) {
            acc.x += wA[j] * aA[j].x; acc.y += wA[j] * aA[j].y;
            acc.z += wA[j] * aA[j].z; acc.w += wA[j] * aA[j].w;
        }
        #pragma unroll
        for (int j = 0; j < KB; ++j) {
            aA[j] = *(const float4*)&A[(size_t)(k + KB + j) * 128 + r0];
            wA[j] = wsp[(k + KB + j) * 8];
        }
        #pragma unroll
        for (int j = 0; j < KB; ++j) {
            acc.x += wB[j] * aB[j].x; acc.y += wB[j] * aB[j].y;
            acc.z += wB[j] * aB[j].z; acc.w += wB[j] * aB[j].w;
        }
    }
    #pragma unroll
    for (int j = 0; j < KB; ++j) {
        aB[j] = *(const float4*)&A[(size_t)(496 + j) * 128 + r0];
        wB[j] = wsp[(496 + j) * 8];
    }
    #pragma unroll
    for (int j = 0; j < KB; ++j) {
        acc.x += wA[j] * aA[j].x; acc.y += wA[j] * aA[j].y;
        acc.z += wA[j] * aA[j].z; acc.w += wA[j] * aA[j].w;
    }
    #pragma unroll
    for (int j = 0; j < KB; ++j) {
        acc.x += wB[j] * aB[j].x; acc.y += wB[j] * aB[j].y;
        acc.z += wB[j] * aB[j].z; acc.w += wB[j] * aB[j].w;
    }
}

__device__ __forceinline__ void acc_half2(const float* __restrict__ A,
                                          const float* __restrict__ wsp,
                                          int r0, float2& acc)
{
    float2 aA[KB], aB[KB];
    float  wA[KB], wB[KB];
    #pragma unroll
    for (int j = 0; j < KB; ++j) {
        aA[j] = *(const float2*)&A[(size_t)j * 128 + r0];
        wA[j] = wsp[j * 4];
    }
    #pragma unroll 1
    for (int k = KB; k < 512 - KB; k += 2 * KB) {
        #pragma unroll
        for (int j = 0; j < KB; ++j) {
            aB[j] = *(const float2*)&A[(size_t)(k + j) * 128 + r0];
            wB[j] = wsp[(k + j) * 4];
        }
        #pragma unroll
        for (int j = 0; j < KB; ++j) {
            acc.x += wA[j] * aA[j].x; acc.y += wA[j] * aA[j].y;
        }
        #pragma unroll
        for (int j = 0; j < KB; ++j) {
            aA[j] = *(const float2*)&A[(size_t)(k + KB + j) * 128 + r0];
            wA[j] = wsp[(k + KB + j) * 4];
        }
        #pragma unroll
        for (int j = 0; j < KB; ++j) {
            acc.x += wB[j] * aB[j].x; acc.y += wB[j] * aB[j].y;
        }
    }
    #pragma unroll
    for (int j = 0; j < KB; ++j) {
        aB[j] = *(const float2*)&A[(size_t)(496 + j) * 128 + r0];
        wB[j] = wsp[(496 + j) * 4];
    }
    #pragma unroll
    for (int j = 0; j < KB; ++j) { acc.x += wA[j] * aA[j].x; acc.y += wA[j] * aA[j].y; }
    #pragma unroll
    for (int j = 0; j < KB; ++j) { acc.x += wB[j] * aB[j].x; acc.y += wB[j] * aB[j].y; }
}

// ---------------------------------------------------------------------
// Gates kernel: computes sigmoid gates for L0(step t0) and L1(step t1)
// in one launch (layer-pipelined). grid 256 x 256thr.
// block: which = bx>>6 (0:gu0 1:gr0 2:gu1 3:gr1), col0 = (bx&63)*8.
// Each weight column read by exactly ONE block (no redundancy).
// gr blocks store gr*h directly (grh), since gr is only used as gr*h.
// All state/gate buffers transposed [512][128].
// ---------------------------------------------------------------------
__global__ __launch_bounds__(256) void k_gates(
    const float* __restrict__ xT,
    const float* __restrict__ h0p, const float* __restrict__ h1p,
    const float* __restrict__ Wu0, const float* __restrict__ bu0,
    const float* __restrict__ Wr0, const float* __restrict__ br0,
    const float* __restrict__ Wu1, const float* __restrict__ bu1,
    const float* __restrict__ Wr1, const float* __restrict__ br1,
    float* __restrict__ gu0T, float* __restrict__ grh0T,
    float* __restrict__ gu1T, float* __restrict__ grh1T,
    int doL0, int doL1)
{
    __shared__ float Ws[1024 * 8];
    const int bx = blockIdx.x;
    const int which = bx >> 6, col0 = (bx & 63) * 8;
    if (which < 2) { if (!doL0) return; } else { if (!doL1) return; }

    const float *W, *bias, *A0, *A1, *hb;
    float* outT;
    switch (which) {
        case 0:  W = Wu0; bias = bu0; outT = gu0T;  A0 = xT;  A1 = h0p; hb = nullptr; break;
        case 1:  W = Wr0; bias = br0; outT = grh0T; A0 = xT;  A1 = h0p; hb = h0p;     break;
        case 2:  W = Wu1; bias = bu1; outT = gu1T;  A0 = h0p; A1 = h1p; hb = nullptr; break;
        default: W = Wr1; bias = br1; outT = grh1T; A0 = h0p; A1 = h1p; hb = h1p;     break;
    }

    const int tid = threadIdx.x;
    for (int idx = tid; idx < 2048; idx += 256) {        // 1024k x 8c floats
        int k = idx >> 1, c4 = (idx & 1) * 4;
        *(float4*)&Ws[k * 8 + c4] = *(const float4*)&W[(size_t)k * 512 + col0 + c4];
    }
    __syncthreads();

    const int c = tid >> 5, r0 = (tid & 31) * 4;
    float4 acc = {0.f, 0.f, 0.f, 0.f};
    acc_half4(A0, &Ws[c], r0, acc);
    acc_half4(A1, &Ws[512 * 8 + c], r0, acc);

    float b = bias[col0 + c];
    float4 o;
    o.x = sigmoidf_(acc.x + b); o.y = sigmoidf_(acc.y + b);
    o.z = sigmoidf_(acc.z + b); o.w = sigmoidf_(acc.w + b);
    size_t bofs = (size_t)(col0 + c) * 128 + r0;
    if (hb) {
        float4 h = *(const float4*)&hb[bofs];
        o.x *= h.x; o.y *= h.y; o.z *= h.z; o.w *= h.w;
    }
    *(float4*)&outT[bofs] = o;
}

// ---------------------------------------------------------------------
// Cand+combine kernel for L0(t0) and L1(t1), plus x pre-gather for t0+1.
// grid 272 x 256thr: bx<256 GEMM (which=bx>>7, col0=(bx&127)*4),
//                    bx>=256: 16 gather blocks.
// ---------------------------------------------------------------------
__global__ __launch_bounds__(256) void k_cand(
    const float* __restrict__ xT,
    const float* __restrict__ h0p, const float* __restrict__ h1p,
    float* __restrict__ h0c, float* __restrict__ h1c,
    const float* __restrict__ Wc0, const float* __restrict__ bc0,
    const float* __restrict__ Wc1, const float* __restrict__ bc1,
    const float* __restrict__ gu0T, const float* __restrict__ grh0T,
    const float* __restrict__ gu1T, const float* __restrict__ grh1T,
    unsigned short* __restrict__ s1bf,
    float* __restrict__ outS,
    const int* __restrict__ toks, const float* __restrict__ emb,
    float* __restrict__ xTn,
    int t0, int t1, int doL0, int doL1)
{
    const int bx = blockIdx.x;
    if (bx >= 256) {
        int tn = t0 + 1;
        if (tn > TT - 1) return;
        xgather_body(toks, emb, tn, xTn, bx - 256);
        return;
    }

    __shared__ float Ws[1024 * 4];
    const int which = bx >> 7, col0 = (bx & 127) * 4;
    if (which == 0) { if (!doL0) return; } else { if (!doL1) return; }

    const float *W, *bias, *A0, *A1, *guT, *hb;
    float* hc;
    if (which == 0) { W = Wc0; bias = bc0; A0 = xT;  A1 = grh0T; guT = gu0T; hb = h0p; hc = h0c; }
    else            { W = Wc1; bias = bc1; A0 = h0p; A1 = grh1T; guT = gu1T; hb = h1p; hc = h1c; }

    const int tid = threadIdx.x;
    for (int k = tid; k < 1024; k += 256)
        *(float4*)&Ws[k * 4] = *(const float4*)&W[(size_t)k * 512 + col0];
    __syncthreads();

    const int c = tid >> 6, r0 = (tid & 63) * 2;
    float2 acc = {0.f, 0.f};
    acc_half2(A0, &Ws[c], r0, acc);
    acc_half2(A1, &Ws[512 * 4 + c], r0, acc);

    const int col = col0 + c;
    float b = bias[col];
    float2 hh;
    hh.x = tanhf(acc.x + b);
    hh.y = tanhf(acc.y + b);
    size_t bofs = (size_t)col * 128 + r0;
    float2 gu = *(const float2*)&guT[bofs];
    float2 h  = *(const float2*)&hb[bofs];
    float2 o;
    o.x = gu.x * h.x + (1.f - gu.x) * hh.x;
    o.y = gu.y * h.y + (1.f - gu.y) * hh.y;
    *(float2*)&hc[bofs] = o;

    if (which == 1) {
        size_t sb = (size_t)t1 * BB * HIDD + (size_t)r0 * 512 + col;
        s1bf[sb]       = f2bfu(o.x);
        s1bf[sb + 512] = f2bfu(o.y);
        if (t1 == TT - 1) {
            outS[(size_t)BB * HIDD + (size_t)r0 * 512 + col]       = o.x;
            outS[(size_t)BB * HIDD + (size_t)(r0 + 1) * 512 + col] = o.y;
        }
    } else if (t0 == TT - 1) {
        outS[(size_t)r0 * 512 + col]       = o.x;
        outS[(size_t)(r0 + 1) * 512 + col] = o.y;
    }
}

// =====================================================================
// Wout transpose+convert: fp32 [512][10000] -> bf16 [10000][512].
// =====================================================================
__global__ __launch_bounds__(256) void k_wT(const float* __restrict__ W,
                                            unsigned short* __restrict__ wT)
{
    __shared__ float T[32][33];
    const int tid = threadIdx.x;
    const int n0 = blockIdx.x * 32, k0 = blockIdx.y * 32;
    {
        int r = tid >> 3, c4 = (tid & 7) * 4;
        float4 v = {0.f, 0.f, 0.f, 0.f};
        if (n0 + c4 + 3 < VOCAB)
            v = *(const float4*)&W[(size_t)(k0 + r) * VOCAB + n0 + c4];
        else {
            if (n0 + c4 + 0 < VOCAB) v.x = W[(size_t)(k0 + r) * VOCAB + n0 + c4 + 0];
            if (n0 + c4 + 1 < VOCAB) v.y = W[(size_t)(k0 + r) * VOCAB + n0 + c4 + 1];
            if (n0 + c4 + 2 < VOCAB) v.z = W[(size_t)(k0 + r) * VOCAB + n0 + c4 + 2];
        }
        T[r][c4 + 0] = v.x; T[r][c4 + 1] = v.y; T[r][c4 + 2] = v.z; T[r][c4 + 3] = v.w;
    }
    __syncthreads();
    {
        int rn = tid >> 3, c4 = (tid & 7) * 4;
        if (n0 + rn < VOCAB) {
            ushort4 u;
            u.x = f2bfu(T[c4 + 0][rn]);
            u.y = f2bfu(T[c4 + 1][rn]);
            u.z = f2bfu(T[c4 + 2][rn]);
            u.w = f2bfu(T[c4 + 3][rn]);
            *(ushort4*)&wT[(size_t)(n0 + rn) * 512 + k0 + c4] = u;
        }
    }
}

// =====================================================================
// MFMA bf16 logits: grid (79, 25)
// =====================================================================
__global__ __launch_bounds__(256) void k_logits(const unsigned short* __restrict__ A,
                                                const unsigned short* __restrict__ Bt,
                                                const float* __restrict__ bias,
                                                float* __restrict__ out)
{
    __shared__ unsigned short As16[128][40];
    __shared__ unsigned short Bs16[128][40];
    const int tid = threadIdx.x;
    const int lane = tid & 63, w = tid >> 6;
    const int quad = lane >> 4, l15 = lane & 15;
    const int n0 = blockIdx.x * 128, m0 = blockIdx.y * 128;

    f32x4 acc[8][2];
    #pragma unroll
    for (int i = 0; i < 8; ++i)
        #pragma unroll
        for (int j = 0; j < 2; ++j) acc[i][j] = (f32x4){0.f, 0.f, 0.f, 0.f};

    for (int k0 = 0; k0 < 512; k0 += 32) {
        #pragma unroll
        for (int l = 0; l < 4; ++l) {
            int idx = tid + l * 256;
            int r = idx >> 3, c8 = (idx & 7) * 4;
            *(ushort4*)&As16[r][c8] =
                *(const ushort4*)&A[(size_t)(m0 + r) * 512 + k0 + c8];
            ushort4 bv = {0, 0, 0, 0};
            if (n0 + r < VOCAB)
                bv = *(const ushort4*)&Bt[(size_t)(n0 + r) * 512 + k0 + c8];
            *(ushort4*)&Bs16[r][c8] = bv;
        }
        __syncthreads();
        bf16x8 bfrag[2];
        #pragma unroll
        for (int nt = 0; nt < 2; ++nt)
            bfrag[nt] = *(const bf16x8*)&Bs16[w * 32 + nt * 16 + l15][quad * 8];
        #pragma unroll
        for (int mt = 0; mt < 8; ++mt) {
            bf16x8 afrag = *(const bf16x8*)&As16[mt * 16 + l15][quad * 8];
            acc[mt][0] = __builtin_amdgcn_mfma_f32_16x16x32_bf16(afrag, bfrag[0], acc[mt][0], 0, 0, 0);
            acc[mt][1] = __builtin_amdgcn_mfma_f32_16x16x32_bf16(afrag, bfrag[1], acc[mt][1], 0, 0, 0);
        }
        __syncthreads();
    }

    #pragma unroll
    for (int nt = 0; nt < 2; ++nt) {
        int n = n0 + w * 32 + nt * 16 + l15;
        if (n < VOCAB) {
            float bo = bias[n];
            #pragma unroll
            for (int mt = 0; mt < 8; ++mt) {
                #pragma unroll
                for (int r = 0; r < 4; ++r) {
                    int m = m0 + mt * 16 + quad * 4 + r;
                    int tt = m >> 7, bb = m & 127;
                    out[(size_t)bb * (TT * VOCAB) + (size_t)tt * VOCAB + n] =
                        acc[mt][nt][r] + bo;
                }
            }
        }
    }
}

extern "C" void kernel_launch(void* const* d_in, const int* in_sizes, int n_in,
                              void* d_out, int out_size, void* d_ws, size_t ws_size,
                              hipStream_t stream)
{
    const float* vgg  = (const float*)d_in[0];
    const int*   toks = (const int*)d_in[1];
    const float* emb  = (const float*)d_in[3];
    const float* Win  = (const float*)d_in[4];
    const float* bin  = (const float*)d_in[5];
    const float* Wu0  = (const float*)d_in[6];
    const float* bu0  = (const float*)d_in[7];
    const float* Wr0  = (const float*)d_in[8];
    const float* br0  = (const float*)d_in[9];
    const float* Wc0  = (const float*)d_in[10];
    const float* bc0  = (const float*)d_in[11];
    const float* Wu1  = (const float*)d_in[12];
    const float* bu1  = (const float*)d_in[13];
    const float* Wr1  = (const float*)d_in[14];
    const float* br1  = (const float*)d_in[15];
    const float* Wc1  = (const float*)d_in[16];
    const float* bc1  = (const float*)d_in[17];
    const float* Wout = (const float*)d_in[18];
    const float* bout = (const float*)d_in[19];

    const size_t S = (size_t)BB * HIDD;          // 65536 floats per state matrix
    float* ws = (float*)d_ws;
    float* h0T[2] = {ws,         ws + S};
    float* h1T[2] = {ws + 2 * S, ws + 3 * S};
    float* xT [2] = {ws + 4 * S, ws + 5 * S};
    float* G      = ws + 6 * S;                  // gu0T, grh0T, gu1T, grh1T
    float* gu0T  = G;
    float* grh0T = G + S;
    float* gu1T  = G + 2 * S;
    float* grh1T = G + 3 * S;
    // G also aliases the 4x[128][512] h0 partial buffer (used only pre-loop)
    unsigned short* s1bf = (unsigned short*)(ws + 10 * S);   // TT*128*512 bf16
    unsigned short* wT   = s1bf + (size_t)TT * BB * HIDD;    // 10000*512 bf16

    float* out = (float*)d_out;
    float* outS = out + (size_t)TT * BB * VOCAB;             // [2][128][512] states

    k_wT<<<dim3(313, 16), 256, 0, stream>>>(Wout, wT);
    k_h0p<<<dim3(8, 64, 4), 256, 0, stream>>>(vgg, Win, G);
    k_h0f<<<dim3(64), 256, 0, stream>>>(G, bin, h0T[1], h1T[1]);
    k_xgather<<<dim3(16), 256, 0, stream>>>(toks, emb, 0, xT[0]);

    // Layer-pipelined recurrence: iteration i runs L0 step t0=i and L1 step t1=i-1.
    for (int i = 0; i <= TT; ++i) {
        int doL0 = (i < TT), doL1 = (i >= 1);
        const float* h0p_ = h0T[(i + 1) & 1];   // h0_{i-1}
        float*       h0c_ = h0T[i & 1];         // h0_i
        const float* h1p_ = h1T[i & 1];         // h1_{i-2}
        float*       h1c_ = h1T[(i + 1) & 1];   // h1_{i-1}
        const float* xc = xT[i & 1];
        float*       xn = xT[(i + 1) & 1];

        k_gates<<<dim3(256), 256, 0, stream>>>(xc, h0p_, h1p_,
                                               Wu0, bu0, Wr0, br0,
                                               Wu1, bu1, Wr1, br1,
                                               gu0T, grh0T, gu1T, grh1T,
                                               doL0, doL1);
        k_cand<<<dim3(272), 256, 0, stream>>>(xc, h0p_, h1p_, h0c_, h1c_,
                                              Wc0, bc0, Wc1, bc1,
                                              gu0T, grh0T, gu1T, grh1T,
                                              s1bf, outS, toks, emb, xn,
                                              i, i - 1, doL0, doL1);
    }

    k_logits<<<dim3(79, 25), 256, 0, stream>>>(s1bf, wT, bout, out);
}

// Round 2
// 1754.210 us; speedup vs baseline: 1.3039x; 1.3039x over previous
//
#include <hip/hip_runtime.h>
#include <hip/hip_bf16.h>

#define BB 128
#define TT 25
#define VOCAB 10000
#define HIDD 512

typedef __hip_bfloat16 bf16;
typedef short bf16x8 __attribute__((ext_vector_type(8)));
typedef float f32x4 __attribute__((ext_vector_type(4)));

__device__ __forceinline__ float sigmoidf_(float x) { return 1.0f / (1.0f + __expf(-x)); }

__device__ __forceinline__ float4 f4_fma(float s, float4 w, float4 a) {
    a.x += s * w.x; a.y += s * w.y; a.z += s * w.z; a.w += s * w.w;
    return a;
}

__device__ __forceinline__ unsigned short f2bfu(float x) {
    bf16 h = __float2bfloat16(x);
    return *reinterpret_cast<unsigned short*>(&h);
}

// =====================================================================
// h0 path (baseline, row-major outputs)
// =====================================================================
__device__ __forceinline__ float4 core128(const float* __restrict__ Wp,
                                          const float* __restrict__ arow)
{
    float4 acc = {0.f, 0.f, 0.f, 0.f};
    #pragma unroll 2
    for (int k = 0; k < 128; k += 8) {
        float4 w[8];
        #pragma unroll
        for (int j = 0; j < 8; ++j)
            w[j] = *(const float4*)(Wp + (size_t)(k + j) * 512);
        #pragma unroll
        for (int j = 0; j < 8; ++j)
            acc = f4_fma(arow[k + j], w[j], acc);
    }
    return acc;
}

#define PHASE_REDUCE(SVAR) \
    __syncthreads(); \
    float4 SVAR; \
    if (tid < 32) { \
        SVAR = red[tid]; \
        _Pragma("unroll") \
        for (int j = 1; j < 8; ++j) { \
            float4 p = red[tid + 32 * j]; \
            SVAR.x += p.x; SVAR.y += p.y; SVAR.z += p.z; SVAR.w += p.w; \
        } \
    }

// vgg[128,4096] @ W_in[4096,512], K split over 4 blocks (z). grid (8,64,4)
__global__ __launch_bounds__(256) void k_h0p(const float* __restrict__ A,
                                             const float* __restrict__ W,
                                             float* __restrict__ partial)
{
    __shared__ float As2[2][1032];
    __shared__ float4 red[256];
    const int tid = threadIdx.x;
    const int n4 = tid & 15, mi = (tid >> 4) & 1, kh = tid >> 5;
    const int m0 = blockIdx.y * 2, col0 = blockIdx.x * 64, kq = blockIdx.z;

    #pragma unroll
    for (int l = 0; l < 2; ++l) {
        int idx = tid + l * 256;
        int r = idx >> 8, c4 = (idx & 255) * 4;
        *(float4*)&As2[r][c4] =
            *(const float4*)&A[(size_t)(m0 + r) * 4096 + kq * 1024 + c4];
    }
    __syncthreads();
    red[tid] = core128(W + (size_t)(kq * 1024 + kh * 128) * 512 + col0 + n4 * 4,
                       &As2[mi][kh * 128]);
    PHASE_REDUCE(s)
    if (tid < 32) {
        int m = m0 + (tid >> 4), cc = col0 + (tid & 15) * 4;
        *(float4*)&partial[((size_t)kq * 128 + m) * 512 + cc] = s;
    }
}

// finalize: sum 4 partials + bias, tanh, write row-major h0/h1
__global__ void k_h0f(const float* __restrict__ partial,
                      const float* __restrict__ bias,
                      float* __restrict__ s0, float* __restrict__ s1)
{
    int i = blockIdx.x * 256 + threadIdx.x;
    size_t e = (size_t)i * 4;
    int cc = (int)(e & 511);
    float4 s = *(const float4*)&partial[e];
    #pragma unroll
    for (int j = 1; j < 4; ++j) {
        float4 p = *(const float4*)&partial[(size_t)j * 128 * 512 + e];
        s.x += p.x; s.y += p.y; s.z += p.z; s.w += p.w;
    }
    float4 b4 = *(const float4*)&bias[cc];
    float4 o;
    o.x = tanhf(s.x + b4.x); o.y = tanhf(s.y + b4.y);
    o.z = tanhf(s.z + b4.z); o.w = tanhf(s.w + b4.w);
    *(float4*)&s0[e] = o;
    *(float4*)&s1[e] = o;
}

// =====================================================================
// Gates kernel: 4 gate-GEMMs (gu0,gr0 @ [x_t;h0p], gu1,gr1 @ [h0p;h1p]),
// layer-pipelined. grid 512 x 512thr.
// bx bits: gate(2) | cb(3, 64 cols) | mb(4, 8 rows). Full K=1024/block.
// 8 waves = 2 row-groups x 4 K-quarters; LDS reduce over K-quarters.
// gr gates store gr*h directly. All buffers row-major [128][512].
// =====================================================================
__global__ __launch_bounds__(512, 4) void k_gates(
    const float* __restrict__ h0p, const float* __restrict__ h1p,
    const int* __restrict__ toks, const float* __restrict__ emb, int t,
    const float* __restrict__ Wu0, const float* __restrict__ bu0,
    const float* __restrict__ Wr0, const float* __restrict__ br0,
    const float* __restrict__ Wu1, const float* __restrict__ bu1,
    const float* __restrict__ Wr1, const float* __restrict__ br1,
    float* __restrict__ gu0, float* __restrict__ grh0,
    float* __restrict__ gu1, float* __restrict__ grh1,
    int doL0, int doL1)
{
    __shared__ float As[8 * 1028];          // 8 rows x K=1024 (+4 pad)
    __shared__ float4 red[4][8][16];        // [kq][row][n4]
    const int bx = blockIdx.x;
    const int gate = bx >> 7;               // 0:gu0 1:gr0 2:gu1 3:gr1
    if (gate < 2) { if (!doL0) return; } else { if (!doL1) return; }
    const int cb = (bx >> 4) & 7, mb = bx & 15;
    const int col0 = cb * 64, m0 = mb * 8;
    const int tid = threadIdx.x;

    // stage A = [A0 ; A1] rows m0..m0+7 (K halves of 512)
    #pragma unroll
    for (int l = 0; l < 4; ++l) {
        int idx = tid + l * 512;            // 0..2047 float4s
        int r2 = idx >> 7;                  // 0..15
        int c4 = (idx & 127) * 4;
        int r = r2 & 7, half = r2 >> 3;
        float4 v;
        if (gate < 2) {
            if (half == 0) {
                int tok = toks[(m0 + r) * TT + t];
                v = *(const float4*)&emb[(size_t)tok * 512 + c4];
            } else {
                v = *(const float4*)&h0p[(size_t)(m0 + r) * 512 + c4];
            }
        } else {
            const float* src = (half == 0) ? h0p : h1p;
            v = *(const float4*)&src[(size_t)(m0 + r) * 512 + c4];
        }
        *(float4*)&As[r * 1028 + half * 512 + c4] = v;
    }
    __syncthreads();

    {
        const int w = tid >> 6, lane = tid & 63;
        const int n4 = lane & 15, rl = lane >> 4;   // 16 col4 x 4 rows
        const int kq = w >> 1, rg = w & 1;          // 4 K-quarters x 2 row-groups
        const int row = rg * 4 + rl;
        const int col = col0 + n4 * 4;
        const float* W = gate == 0 ? Wu0 : gate == 1 ? Wr0 : gate == 2 ? Wu1 : Wr1;
        const float* wp = W + col + (size_t)kq * 256 * 512;
        const float* ap = As + row * 1028 + kq * 256;
        float4 acc0 = {0.f, 0.f, 0.f, 0.f}, acc1 = {0.f, 0.f, 0.f, 0.f};
        #pragma unroll 2
        for (int j = 0; j < 64; ++j) {
            float4 a4 = *(const float4*)(ap + j * 4);
            float4 w0 = *(const float4*)(wp + (j * 4 + 0) * 512);
            float4 w1 = *(const float4*)(wp + (j * 4 + 1) * 512);
            float4 w2 = *(const float4*)(wp + (j * 4 + 2) * 512);
            float4 w3 = *(const float4*)(wp + (j * 4 + 3) * 512);
            acc0 = f4_fma(a4.x, w0, acc0);
            acc1 = f4_fma(a4.y, w1, acc1);
            acc0 = f4_fma(a4.z, w2, acc0);
            acc1 = f4_fma(a4.w, w3, acc1);
        }
        acc0.x += acc1.x; acc0.y += acc1.y; acc0.z += acc1.z; acc0.w += acc1.w;
        red[kq][row][n4] = (float4){acc0.x, acc0.y, acc0.z, acc0.w};
    }
    __syncthreads();

    if (tid < 128) {
        const int row = tid >> 4, n4 = tid & 15;
        float4 s = red[0][row][n4];
        #pragma unroll
        for (int kq = 1; kq < 4; ++kq) {
            float4 p = red[kq][row][n4];
            s.x += p.x; s.y += p.y; s.z += p.z; s.w += p.w;
        }
        const int col = col0 + n4 * 4;
        const int m = m0 + row;
        const float* bias = gate == 0 ? bu0 : gate == 1 ? br0 : gate == 2 ? bu1 : br1;
        float4 b4 = *(const float4*)&bias[col];
        float4 o;
        o.x = sigmoidf_(s.x + b4.x); o.y = sigmoidf_(s.y + b4.y);
        o.z = sigmoidf_(s.z + b4.z); o.w = sigmoidf_(s.w + b4.w);
        size_t ofs = (size_t)m * 512 + col;
        if (gate == 1) {
            float4 h = *(const float4*)&h0p[ofs];
            o.x *= h.x; o.y *= h.y; o.z *= h.z; o.w *= h.w;
        } else if (gate == 3) {
            float4 h = *(const float4*)&h1p[ofs];
            o.x *= h.x; o.y *= h.y; o.z *= h.z; o.w *= h.w;
        }
        float* outp = gate == 0 ? gu0 : gate == 1 ? grh0 : gate == 2 ? gu1 : grh1;
        *(float4*)&outp[ofs] = o;
    }
}

// =====================================================================
// Cand+combine kernel: hh0 = tanh([x;grh0]@Wc0+bc0), h0c = gu0*h0p+(1-gu0)*hh0
//                      hh1 = tanh([h0p;grh1]@Wc1+bc1), h1c = gu1*h1p+(1-gu1)*hh1
// grid 512 x 512thr. bx bits: gate(1) | cb(4, 32 cols) | mb(4, 8 rows).
// 8 waves = 8 K-eighths; LDS reduce.
// =====================================================================
__global__ __launch_bounds__(512, 4) void k_cand(
    const float* __restrict__ h0p, const float* __restrict__ h1p,
    float* __restrict__ h0c, float* __restrict__ h1c,
    const int* __restrict__ toks, const float* __restrict__ emb,
    int t0, int t1,
    const float* __restrict__ Wc0, const float* __restrict__ bc0,
    const float* __restrict__ Wc1, const float* __restrict__ bc1,
    const float* __restrict__ gu0, const float* __restrict__ grh0,
    const float* __restrict__ gu1, const float* __restrict__ grh1,
    unsigned short* __restrict__ s1bf, float* __restrict__ outS,
    int doL0, int doL1)
{
    __shared__ float As[8 * 1028];
    __shared__ float4 red[8][8][8];         // [kq][row][n8]
    const int bx = blockIdx.x;
    const int gate = bx >> 8;               // 0:L0 1:L1
    if (gate == 0) { if (!doL0) return; } else { if (!doL1) return; }
    const int cb = (bx >> 4) & 15, mb = bx & 15;
    const int col0 = cb * 32, m0 = mb * 8;
    const int tid = threadIdx.x;

    #pragma unroll
    for (int l = 0; l < 4; ++l) {
        int idx = tid + l * 512;
        int r2 = idx >> 7;
        int c4 = (idx & 127) * 4;
        int r = r2 & 7, half = r2 >> 3;
        float4 v;
        if (gate == 0) {
            if (half == 0) {
                int tok = toks[(m0 + r) * TT + t0];
                v = *(const float4*)&emb[(size_t)tok * 512 + c4];
            } else {
                v = *(const float4*)&grh0[(size_t)(m0 + r) * 512 + c4];
            }
        } else {
            const float* src = (half == 0) ? h0p : grh1;
            v = *(const float4*)&src[(size_t)(m0 + r) * 512 + c4];
        }
        *(float4*)&As[r * 1028 + half * 512 + c4] = v;
    }
    __syncthreads();

    {
        const int kq = tid >> 6, lane = tid & 63;
        const int n8 = lane & 7, rl = lane >> 3;   // 8 col4 x 8 rows
        const int col = col0 + n8 * 4;
        const float* W = gate ? Wc1 : Wc0;
        const float* wp = W + col + (size_t)kq * 128 * 512;
        const float* ap = As + rl * 1028 + kq * 128;
        float4 acc0 = {0.f, 0.f, 0.f, 0.f}, acc1 = {0.f, 0.f, 0.f, 0.f};
        #pragma unroll 2
        for (int j = 0; j < 32; ++j) {
            float4 a4 = *(const float4*)(ap + j * 4);
            float4 w0 = *(const float4*)(wp + (j * 4 + 0) * 512);
            float4 w1 = *(const float4*)(wp + (j * 4 + 1) * 512);
            float4 w2 = *(const float4*)(wp + (j * 4 + 2) * 512);
            float4 w3 = *(const float4*)(wp + (j * 4 + 3) * 512);
            acc0 = f4_fma(a4.x, w0, acc0);
            acc1 = f4_fma(a4.y, w1, acc1);
            acc0 = f4_fma(a4.z, w2, acc0);
            acc1 = f4_fma(a4.w, w3, acc1);
        }
        acc0.x += acc1.x; acc0.y += acc1.y; acc0.z += acc1.z; acc0.w += acc1.w;
        red[kq][rl][n8] = (float4){acc0.x, acc0.y, acc0.z, acc0.w};
    }
    __syncthreads();

    if (tid < 64) {
        const int row = tid >> 3, n8 = tid & 7;
        float4 s = red[0][row][n8];
        #pragma unroll
        for (int kq = 1; kq < 8; ++kq) {
            float4 p = red[kq][row][n8];
            s.x += p.x; s.y += p.y; s.z += p.z; s.w += p.w;
        }
        const int col = col0 + n8 * 4;
        const int m = m0 + row;
        const float* bias = gate ? bc1 : bc0;
        float4 b4 = *(const float4*)&bias[col];
        size_t ofs = (size_t)m * 512 + col;
        float4 g  = *(const float4*)&((gate ? gu1 : gu0)[ofs]);
        float4 hv = *(const float4*)&((gate ? h1p : h0p)[ofs]);
        float4 o;
        o.x = g.x * hv.x + (1.f - g.x) * tanhf(s.x + b4.x);
        o.y = g.y * hv.y + (1.f - g.y) * tanhf(s.y + b4.y);
        o.z = g.z * hv.z + (1.f - g.z) * tanhf(s.z + b4.z);
        o.w = g.w * hv.w + (1.f - g.w) * tanhf(s.w + b4.w);
        *(float4*)&((gate ? h1c : h0c)[ofs]) = o;
        if (gate == 1) {
            ushort4 u;
            u.x = f2bfu(o.x); u.y = f2bfu(o.y); u.z = f2bfu(o.z); u.w = f2bfu(o.w);
            *(ushort4*)&s1bf[(size_t)t1 * BB * HIDD + ofs] = u;
            if (t1 == TT - 1)
                *(float4*)&outS[(size_t)BB * HIDD + ofs] = o;
        } else if (t0 == TT - 1) {
            *(float4*)&outS[ofs] = o;
        }
    }
}

// =====================================================================
// Wout transpose+convert: fp32 [512][10000] -> bf16 [10000][512].
// =====================================================================
__global__ __launch_bounds__(256) void k_wT(const float* __restrict__ W,
                                            unsigned short* __restrict__ wT)
{
    __shared__ float T[32][33];
    const int tid = threadIdx.x;
    const int n0 = blockIdx.x * 32, k0 = blockIdx.y * 32;
    {
        int r = tid >> 3, c4 = (tid & 7) * 4;
        float4 v = {0.f, 0.f, 0.f, 0.f};
        if (n0 + c4 + 3 < VOCAB)
            v = *(const float4*)&W[(size_t)(k0 + r) * VOCAB + n0 + c4];
        else {
            if (n0 + c4 + 0 < VOCAB) v.x = W[(size_t)(k0 + r) * VOCAB + n0 + c4 + 0];
            if (n0 + c4 + 1 < VOCAB) v.y = W[(size_t)(k0 + r) * VOCAB + n0 + c4 + 1];
            if (n0 + c4 + 2 < VOCAB) v.z = W[(size_t)(k0 + r) * VOCAB + n0 + c4 + 2];
        }
        T[r][c4 + 0] = v.x; T[r][c4 + 1] = v.y; T[r][c4 + 2] = v.z; T[r][c4 + 3] = v.w;
    }
    __syncthreads();
    {
        int rn = tid >> 3, c4 = (tid & 7) * 4;
        if (n0 + rn < VOCAB) {
            ushort4 u;
            u.x = f2bfu(T[c4 + 0][rn]);
            u.y = f2bfu(T[c4 + 1][rn]);
            u.z = f2bfu(T[c4 + 2][rn]);
            u.w = f2bfu(T[c4 + 3][rn]);
            *(ushort4*)&wT[(size_t)(n0 + rn) * 512 + k0 + c4] = u;
        }
    }
}

// =====================================================================
// MFMA bf16 logits: grid (79, 25)
// =====================================================================
__global__ __launch_bounds__(256) void k_logits(const unsigned short* __restrict__ A,
                                                const unsigned short* __restrict__ Bt,
                                                const float* __restrict__ bias,
                                                float* __restrict__ out)
{
    __shared__ unsigned short As16[128][40];
    __shared__ unsigned short Bs16[128][40];
    const int tid = threadIdx.x;
    const int lane = tid & 63, w = tid >> 6;
    const int quad = lane >> 4, l15 = lane & 15;
    const int n0 = blockIdx.x * 128, m0 = blockIdx.y * 128;

    f32x4 acc[8][2];
    #pragma unroll
    for (int i = 0; i < 8; ++i)
        #pragma unroll
        for (int j = 0; j < 2; ++j) acc[i][j] = (f32x4){0.f, 0.f, 0.f, 0.f};

    for (int k0 = 0; k0 < 512; k0 += 32) {
        #pragma unroll
        for (int l = 0; l < 4; ++l) {
            int idx = tid + l * 256;
            int r = idx >> 3, c8 = (idx & 7) * 4;
            *(ushort4*)&As16[r][c8] =
                *(const ushort4*)&A[(size_t)(m0 + r) * 512 + k0 + c8];
            ushort4 bv = {0, 0, 0, 0};
            if (n0 + r < VOCAB)
                bv = *(const ushort4*)&Bt[(size_t)(n0 + r) * 512 + k0 + c8];
            *(ushort4*)&Bs16[r][c8] = bv;
        }
        __syncthreads();
        bf16x8 bfrag[2];
        #pragma unroll
        for (int nt = 0; nt < 2; ++nt)
            bfrag[nt] = *(const bf16x8*)&Bs16[w * 32 + nt * 16 + l15][quad * 8];
        #pragma unroll
        for (int mt = 0; mt < 8; ++mt) {
            bf16x8 afrag = *(const bf16x8*)&As16[mt * 16 + l15][quad * 8];
            acc[mt][0] = __builtin_amdgcn_mfma_f32_16x16x32_bf16(afrag, bfrag[0], acc[mt][0], 0, 0, 0);
            acc[mt][1] = __builtin_amdgcn_mfma_f32_16x16x32_bf16(afrag, bfrag[1], acc[mt][1], 0, 0, 0);
        }
        __syncthreads();
    }

    #pragma unroll
    for (int nt = 0; nt < 2; ++nt) {
        int n = n0 + w * 32 + nt * 16 + l15;
        if (n < VOCAB) {
            float bo = bias[n];
            #pragma unroll
            for (int mt = 0; mt < 8; ++mt) {
                #pragma unroll
                for (int r = 0; r < 4; ++r) {
                    int m = m0 + mt * 16 + quad * 4 + r;
                    int tt = m >> 7, bb = m & 127;
                    out[(size_t)bb * (TT * VOCAB) + (size_t)tt * VOCAB + n] =
                        acc[mt][nt][r] + bo;
                }
            }
        }
    }
}

extern "C" void kernel_launch(void* const* d_in, const int* in_sizes, int n_in,
                              void* d_out, int out_size, void* d_ws, size_t ws_size,
                              hipStream_t stream)
{
    const float* vgg  = (const float*)d_in[0];
    const int*   toks = (const int*)d_in[1];
    const float* emb  = (const float*)d_in[3];
    const float* Win  = (const float*)d_in[4];
    const float* bin  = (const float*)d_in[5];
    const float* Wu0  = (const float*)d_in[6];
    const float* bu0  = (const float*)d_in[7];
    const float* Wr0  = (const float*)d_in[8];
    const float* br0  = (const float*)d_in[9];
    const float* Wc0  = (const float*)d_in[10];
    const float* bc0  = (const float*)d_in[11];
    const float* Wu1  = (const float*)d_in[12];
    const float* bu1  = (const float*)d_in[13];
    const float* Wr1  = (const float*)d_in[14];
    const float* br1  = (const float*)d_in[15];
    const float* Wc1  = (const float*)d_in[16];
    const float* bc1  = (const float*)d_in[17];
    const float* Wout = (const float*)d_in[18];
    const float* bout = (const float*)d_in[19];

    const size_t S = (size_t)BB * HIDD;      // 65536 floats
    float* ws = (float*)d_ws;
    float* h0b[2] = {ws,         ws + S};
    float* h1b[2] = {ws + 2 * S, ws + 3 * S};
    float* gu0  = ws + 4 * S;
    float* grh0 = ws + 5 * S;
    float* gu1  = ws + 6 * S;
    float* grh1 = ws + 7 * S;
    // gu0..grh1 (4x 128*512) double as the h0 partial buffer pre-loop
    unsigned short* s1bf = (unsigned short*)(ws + 8 * S);   // TT*128*512 bf16
    unsigned short* wT   = s1bf + (size_t)TT * BB * HIDD;   // 10000*512 bf16

    float* out = (float*)d_out;
    float* outS = out + (size_t)TT * BB * VOCAB;            // [2][128][512]

    k_wT<<<dim3(313, 16), 256, 0, stream>>>(Wout, wT);
    k_h0p<<<dim3(8, 64, 4), 256, 0, stream>>>(vgg, Win, gu0);
    k_h0f<<<dim3(64), 256, 0, stream>>>(gu0, bin, h0b[1], h1b[1]);

    // Layer-pipelined recurrence: iteration i = L0 step t0=i and L1 step t1=i-1.
    for (int i = 0; i <= TT; ++i) {
        int doL0 = (i < TT), doL1 = (i >= 1);
        const float* h0p_ = h0b[(i + 1) & 1];   // h0_{i-1}
        float*       h0c_ = h0b[i & 1];         // h0_i
        const float* h1p_ = h1b[i & 1];         // h1_{i-2}
        float*       h1c_ = h1b[(i + 1) & 1];   // h1_{i-1}

        k_gates<<<dim3(512), 512, 0, stream>>>(h0p_, h1p_, toks, emb, i,
                                               Wu0, bu0, Wr0, br0,
                                               Wu1, bu1, Wr1, br1,
                                               gu0, grh0, gu1, grh1,
                                               doL0, doL1);
        k_cand<<<dim3(512), 512, 0, stream>>>(h0p_, h1p_, h0c_, h1c_,
                                              toks, emb, i, i - 1,
                                              Wc0, bc0, Wc1, bc1,
                                              gu0, grh0, gu1, grh1,
                                              s1bf, outS, doL0, doL1);
    }

    k_logits<<<dim3(79, 25), 256, 0, stream>>>(s1bf, wT, bout, out);
}

// Round 3
// 1086.385 us; speedup vs baseline: 2.1055x; 1.6147x over previous
//
#include <hip/hip_runtime.h>
#include <hip/hip_bf16.h>

#define BB 128
#define TT 25
#define VOCAB 10000
#define HIDD 512

typedef __hip_bfloat16 bf16;
typedef short bf16x8 __attribute__((ext_vector_type(8)));
typedef float f32x4 __attribute__((ext_vector_type(4)));

__device__ __forceinline__ float sigmoidf_(float x) { return 1.0f / (1.0f + __expf(-x)); }

__device__ __forceinline__ float4 f4_fma(float s, float4 w, float4 a) {
    a.x += s * w.x; a.y += s * w.y; a.z += s * w.z; a.w += s * w.w;
    return a;
}

__device__ __forceinline__ unsigned short f2bfu(float x) {
    bf16 h = __float2bfloat16(x);
    return *reinterpret_cast<unsigned short*>(&h);
}

// =====================================================================
// h0 path (unchanged)
// =====================================================================
__device__ __forceinline__ float4 core128(const float* __restrict__ Wp,
                                          const float* __restrict__ arow)
{
    float4 acc = {0.f, 0.f, 0.f, 0.f};
    #pragma unroll 2
    for (int k = 0; k < 128; k += 8) {
        float4 w[8];
        #pragma unroll
        for (int j = 0; j < 8; ++j)
            w[j] = *(const float4*)(Wp + (size_t)(k + j) * 512);
        #pragma unroll
        for (int j = 0; j < 8; ++j)
            acc = f4_fma(arow[k + j], w[j], acc);
    }
    return acc;
}

#define PHASE_REDUCE(SVAR) \
    __syncthreads(); \
    float4 SVAR; \
    if (tid < 32) { \
        SVAR = red[tid]; \
        _Pragma("unroll") \
        for (int j = 1; j < 8; ++j) { \
            float4 p = red[tid + 32 * j]; \
            SVAR.x += p.x; SVAR.y += p.y; SVAR.z += p.z; SVAR.w += p.w; \
        } \
    }

// vgg[128,4096] @ W_in[4096,512], K split over 4 blocks (z). grid (8,64,4)
__global__ __launch_bounds__(256) void k_h0p(const float* __restrict__ A,
                                             const float* __restrict__ W,
                                             float* __restrict__ partial)
{
    __shared__ float As2[2][1032];
    __shared__ float4 red[256];
    const int tid = threadIdx.x;
    const int n4 = tid & 15, mi = (tid >> 4) & 1, kh = tid >> 5;
    const int m0 = blockIdx.y * 2, col0 = blockIdx.x * 64, kq = blockIdx.z;

    #pragma unroll
    for (int l = 0; l < 2; ++l) {
        int idx = tid + l * 256;
        int r = idx >> 8, c4 = (idx & 255) * 4;
        *(float4*)&As2[r][c4] =
            *(const float4*)&A[(size_t)(m0 + r) * 4096 + kq * 1024 + c4];
    }
    __syncthreads();
    red[tid] = core128(W + (size_t)(kq * 1024 + kh * 128) * 512 + col0 + n4 * 4,
                       &As2[mi][kh * 128]);
    PHASE_REDUCE(s)
    if (tid < 32) {
        int m = m0 + (tid >> 4), cc = col0 + (tid & 15) * 4;
        *(float4*)&partial[((size_t)kq * 128 + m) * 512 + cc] = s;
    }
}

// finalize: sum 4 partials + bias, tanh, write row-major h0/h1
__global__ void k_h0f(const float* __restrict__ partial,
                      const float* __restrict__ bias,
                      float* __restrict__ s0, float* __restrict__ s1)
{
    int i = blockIdx.x * 256 + threadIdx.x;
    size_t e = (size_t)i * 4;
    int cc = (int)(e & 511);
    float4 s = *(const float4*)&partial[e];
    #pragma unroll
    for (int j = 1; j < 4; ++j) {
        float4 p = *(const float4*)&partial[(size_t)j * 128 * 512 + e];
        s.x += p.x; s.y += p.y; s.z += p.z; s.w += p.w;
    }
    float4 b4 = *(const float4*)&bias[cc];
    float4 o;
    o.x = tanhf(s.x + b4.x); o.y = tanhf(s.y + b4.y);
    o.z = tanhf(s.z + b4.z); o.w = tanhf(s.w + b4.w);
    *(float4*)&s0[e] = o;
    *(float4*)&s1[e] = o;
}

// =====================================================================
// Gates kernel. grid 512 x 512thr.
// bx = mb(4b) | gate(2b) | cb(3b)  ->  XCD = bx%8 = cb  (weight tile
// (gate,cb) pinned to one XCD; 1 MB distinct weights per XCD -> L2-resident).
// 8 waves = 8 K-eighths; each wave covers all 8 rows (2 acc sets, rows
// rl and rl+4) so the weight tile is read exactly once per block.
// gr gates store gr*h directly. All buffers row-major [128][512].
// =====================================================================
__global__ __launch_bounds__(512, 4) void k_gates(
    const float* __restrict__ h0p, const float* __restrict__ h1p,
    const int* __restrict__ toks, const float* __restrict__ emb, int t,
    const float* __restrict__ Wu0, const float* __restrict__ bu0,
    const float* __restrict__ Wr0, const float* __restrict__ br0,
    const float* __restrict__ Wu1, const float* __restrict__ bu1,
    const float* __restrict__ Wr1, const float* __restrict__ br1,
    float* __restrict__ gu0, float* __restrict__ grh0,
    float* __restrict__ gu1, float* __restrict__ grh1,
    int doL0, int doL1)
{
    __shared__ float As[8 * 1028];          // 8 rows x K=1024 (+4 pad)
    __shared__ float4 red[8][8][16];        // [kq][row][n4] = 16 KB
    const int bx = blockIdx.x;
    const int cb = bx & 7, gate = (bx >> 3) & 3, mb = bx >> 5;
    if (gate < 2) { if (!doL0) return; } else { if (!doL1) return; }
    const int col0 = cb * 64, m0 = mb * 8;
    const int tid = threadIdx.x;

    // stage A = [A0 ; A1] rows m0..m0+7 (two K-halves of 512)
    #pragma unroll
    for (int l = 0; l < 4; ++l) {
        int idx = tid + l * 512;            // 0..2047 float4s
        int r2 = idx >> 7;                  // 0..15
        int c4 = (idx & 127) * 4;
        int r = r2 & 7, half = r2 >> 3;
        float4 v;
        if (gate < 2) {
            if (half == 0) {
                int tok = toks[(m0 + r) * TT + t];
                v = *(const float4*)&emb[(size_t)tok * 512 + c4];
            } else {
                v = *(const float4*)&h0p[(size_t)(m0 + r) * 512 + c4];
            }
        } else {
            const float* src = (half == 0) ? h0p : h1p;
            v = *(const float4*)&src[(size_t)(m0 + r) * 512 + c4];
        }
        *(float4*)&As[r * 1028 + half * 512 + c4] = v;
    }
    __syncthreads();

    {
        const int kq = tid >> 6, lane = tid & 63;
        const int n4 = lane & 15, rl = lane >> 4;   // 16 col4 x 4 row-pairs
        const int col = col0 + n4 * 4;
        const float* W = gate == 0 ? Wu0 : gate == 1 ? Wr0 : gate == 2 ? Wu1 : Wr1;
        const float* wp = W + col + (size_t)kq * 128 * 512;
        const float* ap0 = As + rl * 1028 + kq * 128;
        const float* ap1 = As + (rl + 4) * 1028 + kq * 128;
        float4 acc0a = {0.f,0.f,0.f,0.f}, acc0b = {0.f,0.f,0.f,0.f};
        float4 acc1a = {0.f,0.f,0.f,0.f}, acc1b = {0.f,0.f,0.f,0.f};
        #pragma unroll 2
        for (int j = 0; j < 32; ++j) {
            float4 a0 = *(const float4*)(ap0 + j * 4);
            float4 a1 = *(const float4*)(ap1 + j * 4);
            float4 w0 = *(const float4*)(wp + (j * 4 + 0) * 512);
            float4 w1 = *(const float4*)(wp + (j * 4 + 1) * 512);
            float4 w2 = *(const float4*)(wp + (j * 4 + 2) * 512);
            float4 w3 = *(const float4*)(wp + (j * 4 + 3) * 512);
            acc0a = f4_fma(a0.x, w0, acc0a); acc1a = f4_fma(a1.x, w0, acc1a);
            acc0b = f4_fma(a0.y, w1, acc0b); acc1b = f4_fma(a1.y, w1, acc1b);
            acc0a = f4_fma(a0.z, w2, acc0a); acc1a = f4_fma(a1.z, w2, acc1a);
            acc0b = f4_fma(a0.w, w3, acc0b); acc1b = f4_fma(a1.w, w3, acc1b);
        }
        float4 s0v, s1v;
        s0v.x = acc0a.x + acc0b.x; s0v.y = acc0a.y + acc0b.y;
        s0v.z = acc0a.z + acc0b.z; s0v.w = acc0a.w + acc0b.w;
        s1v.x = acc1a.x + acc1b.x; s1v.y = acc1a.y + acc1b.y;
        s1v.z = acc1a.z + acc1b.z; s1v.w = acc1a.w + acc1b.w;
        red[kq][rl][n4] = s0v;
        red[kq][rl + 4][n4] = s1v;
    }
    __syncthreads();

    if (tid < 128) {
        const int row = tid >> 4, n4 = tid & 15;
        float4 s = red[0][row][n4];
        #pragma unroll
        for (int kq = 1; kq < 8; ++kq) {
            float4 p = red[kq][row][n4];
            s.x += p.x; s.y += p.y; s.z += p.z; s.w += p.w;
        }
        const int col = col0 + n4 * 4;
        const int m = m0 + row;
        const float* bias = gate == 0 ? bu0 : gate == 1 ? br0 : gate == 2 ? bu1 : br1;
        float4 b4 = *(const float4*)&bias[col];
        float4 o;
        o.x = sigmoidf_(s.x + b4.x); o.y = sigmoidf_(s.y + b4.y);
        o.z = sigmoidf_(s.z + b4.z); o.w = sigmoidf_(s.w + b4.w);
        size_t ofs = (size_t)m * 512 + col;
        if (gate == 1) {
            float4 h = *(const float4*)&h0p[ofs];
            o.x *= h.x; o.y *= h.y; o.z *= h.z; o.w *= h.w;
        } else if (gate == 3) {
            float4 h = *(const float4*)&h1p[ofs];
            o.x *= h.x; o.y *= h.y; o.z *= h.z; o.w *= h.w;
        }
        float* outp = gate == 0 ? gu0 : gate == 1 ? grh0 : gate == 2 ? gu1 : grh1;
        *(float4*)&outp[ofs] = o;
    }
}

// =====================================================================
// Cand+combine kernel: same structure as k_gates, 2 matrices.
// grid 256 x 512thr. bx = mb(4b) | gate(1b) | cb(3b) -> XCD = cb.
// =====================================================================
__global__ __launch_bounds__(512, 2) void k_cand(
    const float* __restrict__ h0p, const float* __restrict__ h1p,
    float* __restrict__ h0c, float* __restrict__ h1c,
    const int* __restrict__ toks, const float* __restrict__ emb,
    int t0, int t1,
    const float* __restrict__ Wc0, const float* __restrict__ bc0,
    const float* __restrict__ Wc1, const float* __restrict__ bc1,
    const float* __restrict__ gu0, const float* __restrict__ grh0,
    const float* __restrict__ gu1, const float* __restrict__ grh1,
    unsigned short* __restrict__ s1bf, float* __restrict__ outS,
    int doL0, int doL1)
{
    __shared__ float As[8 * 1028];
    __shared__ float4 red[8][8][16];
    const int bx = blockIdx.x;
    const int cb = bx & 7, gate = (bx >> 3) & 1, mb = bx >> 4;
    if (gate == 0) { if (!doL0) return; } else { if (!doL1) return; }
    const int col0 = cb * 64, m0 = mb * 8;
    const int tid = threadIdx.x;

    #pragma unroll
    for (int l = 0; l < 4; ++l) {
        int idx = tid + l * 512;
        int r2 = idx >> 7;
        int c4 = (idx & 127) * 4;
        int r = r2 & 7, half = r2 >> 3;
        float4 v;
        if (gate == 0) {
            if (half == 0) {
                int tok = toks[(m0 + r) * TT + t0];
                v = *(const float4*)&emb[(size_t)tok * 512 + c4];
            } else {
                v = *(const float4*)&grh0[(size_t)(m0 + r) * 512 + c4];
            }
        } else {
            const float* src = (half == 0) ? h0p : grh1;
            v = *(const float4*)&src[(size_t)(m0 + r) * 512 + c4];
        }
        *(float4*)&As[r * 1028 + half * 512 + c4] = v;
    }
    __syncthreads();

    {
        const int kq = tid >> 6, lane = tid & 63;
        const int n4 = lane & 15, rl = lane >> 4;
        const int col = col0 + n4 * 4;
        const float* W = gate ? Wc1 : Wc0;
        const float* wp = W + col + (size_t)kq * 128 * 512;
        const float* ap0 = As + rl * 1028 + kq * 128;
        const float* ap1 = As + (rl + 4) * 1028 + kq * 128;
        float4 acc0a = {0.f,0.f,0.f,0.f}, acc0b = {0.f,0.f,0.f,0.f};
        float4 acc1a = {0.f,0.f,0.f,0.f}, acc1b = {0.f,0.f,0.f,0.f};
        #pragma unroll 2
        for (int j = 0; j < 32; ++j) {
            float4 a0 = *(const float4*)(ap0 + j * 4);
            float4 a1 = *(const float4*)(ap1 + j * 4);
            float4 w0 = *(const float4*)(wp + (j * 4 + 0) * 512);
            float4 w1 = *(const float4*)(wp + (j * 4 + 1) * 512);
            float4 w2 = *(const float4*)(wp + (j * 4 + 2) * 512);
            float4 w3 = *(const float4*)(wp + (j * 4 + 3) * 512);
            acc0a = f4_fma(a0.x, w0, acc0a); acc1a = f4_fma(a1.x, w0, acc1a);
            acc0b = f4_fma(a0.y, w1, acc0b); acc1b = f4_fma(a1.y, w1, acc1b);
            acc0a = f4_fma(a0.z, w2, acc0a); acc1a = f4_fma(a1.z, w2, acc1a);
            acc0b = f4_fma(a0.w, w3, acc0b); acc1b = f4_fma(a1.w, w3, acc1b);
        }
        float4 s0v, s1v;
        s0v.x = acc0a.x + acc0b.x; s0v.y = acc0a.y + acc0b.y;
        s0v.z = acc0a.z + acc0b.z; s0v.w = acc0a.w + acc0b.w;
        s1v.x = acc1a.x + acc1b.x; s1v.y = acc1a.y + acc1b.y;
        s1v.z = acc1a.z + acc1b.z; s1v.w = acc1a.w + acc1b.w;
        red[kq][rl][n4] = s0v;
        red[kq][rl + 4][n4] = s1v;
    }
    __syncthreads();

    if (tid < 128) {
        const int row = tid >> 4, n4 = tid & 15;
        float4 s = red[0][row][n4];
        #pragma unroll
        for (int kq = 1; kq < 8; ++kq) {
            float4 p = red[kq][row][n4];
            s.x += p.x; s.y += p.y; s.z += p.z; s.w += p.w;
        }
        const int col = col0 + n4 * 4;
        const int m = m0 + row;
        const float* bias = gate ? bc1 : bc0;
        float4 b4 = *(const float4*)&bias[col];
        size_t ofs = (size_t)m * 512 + col;
        float4 g  = *(const float4*)&((gate ? gu1 : gu0)[ofs]);
        float4 hv = *(const float4*)&((gate ? h1p : h0p)[ofs]);
        float4 o;
        o.x = g.x * hv.x + (1.f - g.x) * tanhf(s.x + b4.x);
        o.y = g.y * hv.y + (1.f - g.y) * tanhf(s.y + b4.y);
        o.z = g.z * hv.z + (1.f - g.z) * tanhf(s.z + b4.z);
        o.w = g.w * hv.w + (1.f - g.w) * tanhf(s.w + b4.w);
        *(float4*)&((gate ? h1c : h0c)[ofs]) = o;
        if (gate == 1) {
            ushort4 u;
            u.x = f2bfu(o.x); u.y = f2bfu(o.y); u.z = f2bfu(o.z); u.w = f2bfu(o.w);
            *(ushort4*)&s1bf[(size_t)t1 * BB * HIDD + ofs] = u;
            if (t1 == TT - 1)
                *(float4*)&outS[(size_t)BB * HIDD + ofs] = o;
        } else if (t0 == TT - 1) {
            *(float4*)&outS[ofs] = o;
        }
    }
}

// =====================================================================
// Wout transpose+convert: fp32 [512][10000] -> bf16 [10000][512].
// =====================================================================
__global__ __launch_bounds__(256) void k_wT(const float* __restrict__ W,
                                            unsigned short* __restrict__ wT)
{
    __shared__ float T[32][33];
    const int tid = threadIdx.x;
    const int n0 = blockIdx.x * 32, k0 = blockIdx.y * 32;
    {
        int r = tid >> 3, c4 = (tid & 7) * 4;
        float4 v = {0.f, 0.f, 0.f, 0.f};
        if (n0 + c4 + 3 < VOCAB)
            v = *(const float4*)&W[(size_t)(k0 + r) * VOCAB + n0 + c4];
        else {
            if (n0 + c4 + 0 < VOCAB) v.x = W[(size_t)(k0 + r) * VOCAB + n0 + c4 + 0];
            if (n0 + c4 + 1 < VOCAB) v.y = W[(size_t)(k0 + r) * VOCAB + n0 + c4 + 1];
            if (n0 + c4 + 2 < VOCAB) v.z = W[(size_t)(k0 + r) * VOCAB + n0 + c4 + 2];
        }
        T[r][c4 + 0] = v.x; T[r][c4 + 1] = v.y; T[r][c4 + 2] = v.z; T[r][c4 + 3] = v.w;
    }
    __syncthreads();
    {
        int rn = tid >> 3, c4 = (tid & 7) * 4;
        if (n0 + rn < VOCAB) {
            ushort4 u;
            u.x = f2bfu(T[c4 + 0][rn]);
            u.y = f2bfu(T[c4 + 1][rn]);
            u.z = f2bfu(T[c4 + 2][rn]);
            u.w = f2bfu(T[c4 + 3][rn]);
            *(ushort4*)&wT[(size_t)(n0 + rn) * 512 + k0 + c4] = u;
        }
    }
}

// =====================================================================
// MFMA bf16 logits. grid 2000 1-D:
// bid = (n-group, m-tile) * 8 + xcd; nb = ng*8 + xcd -> XCD-pinned wT slice
// (1.25 MB/XCD -> L2-resident across the 25 m-tiles).
// Register-prefetch of next k-tile overlaps global latency with MFMA.
// =====================================================================
__global__ __launch_bounds__(256) void k_logits(const unsigned short* __restrict__ A,
                                                const unsigned short* __restrict__ Bt,
                                                const float* __restrict__ bias,
                                                float* __restrict__ out)
{
    __shared__ unsigned short As16[128][40];
    __shared__ unsigned short Bs16[128][40];
    const int tid = threadIdx.x;
    const int lane = tid & 63, w = tid >> 6;
    const int quad = lane >> 4, l15 = lane & 15;
    const int bid = blockIdx.x;
    const int xcd = bid & 7;
    const int rest = bid >> 3;              // 0..249
    const int mb = rest % 25;
    const int nb = (rest / 25) * 8 + xcd;   // 0..79
    if (nb >= 79) return;
    const int n0 = nb * 128, m0 = mb * 128;

    f32x4 acc[8][2];
    #pragma unroll
    for (int i = 0; i < 8; ++i)
        #pragma unroll
        for (int j = 0; j < 2; ++j) acc[i][j] = (f32x4){0.f, 0.f, 0.f, 0.f};

    ushort4 pa[4], pb[4];
    #pragma unroll
    for (int l = 0; l < 4; ++l) {
        int idx = tid + l * 256;
        int r = idx >> 3, c8 = (idx & 7) * 4;
        pa[l] = *(const ushort4*)&A[(size_t)(m0 + r) * 512 + c8];
        ushort4 bv = {0, 0, 0, 0};
        if (n0 + r < VOCAB)
            bv = *(const ushort4*)&Bt[(size_t)(n0 + r) * 512 + c8];
        pb[l] = bv;
    }

    for (int k0 = 0; k0 < 512; k0 += 32) {
        #pragma unroll
        for (int l = 0; l < 4; ++l) {
            int idx = tid + l * 256;
            int r = idx >> 3, c8 = (idx & 7) * 4;
            *(ushort4*)&As16[r][c8] = pa[l];
            *(ushort4*)&Bs16[r][c8] = pb[l];
        }
        if (k0 + 32 < 512) {
            #pragma unroll
            for (int l = 0; l < 4; ++l) {
                int idx = tid + l * 256;
                int r = idx >> 3, c8 = (idx & 7) * 4;
                pa[l] = *(const ushort4*)&A[(size_t)(m0 + r) * 512 + k0 + 32 + c8];
                ushort4 bv = {0, 0, 0, 0};
                if (n0 + r < VOCAB)
                    bv = *(const ushort4*)&Bt[(size_t)(n0 + r) * 512 + k0 + 32 + c8];
                pb[l] = bv;
            }
        }
        __syncthreads();
        bf16x8 bfrag[2];
        #pragma unroll
        for (int nt = 0; nt < 2; ++nt)
            bfrag[nt] = *(const bf16x8*)&Bs16[w * 32 + nt * 16 + l15][quad * 8];
        #pragma unroll
        for (int mt = 0; mt < 8; ++mt) {
            bf16x8 afrag = *(const bf16x8*)&As16[mt * 16 + l15][quad * 8];
            acc[mt][0] = __builtin_amdgcn_mfma_f32_16x16x32_bf16(afrag, bfrag[0], acc[mt][0], 0, 0, 0);
            acc[mt][1] = __builtin_amdgcn_mfma_f32_16x16x32_bf16(afrag, bfrag[1], acc[mt][1], 0, 0, 0);
        }
        __syncthreads();
    }

    #pragma unroll
    for (int nt = 0; nt < 2; ++nt) {
        int n = n0 + w * 32 + nt * 16 + l15;
        if (n < VOCAB) {
            float bo = bias[n];
            #pragma unroll
            for (int mt = 0; mt < 8; ++mt) {
                #pragma unroll
                for (int r = 0; r < 4; ++r) {
                    int m = m0 + mt * 16 + quad * 4 + r;
                    int tt = m >> 7, bb = m & 127;
                    out[(size_t)bb * (TT * VOCAB) + (size_t)tt * VOCAB + n] =
                        acc[mt][nt][r] + bo;
                }
            }
        }
    }
}

extern "C" void kernel_launch(void* const* d_in, const int* in_sizes, int n_in,
                              void* d_out, int out_size, void* d_ws, size_t ws_size,
                              hipStream_t stream)
{
    const float* vgg  = (const float*)d_in[0];
    const int*   toks = (const int*)d_in[1];
    const float* emb  = (const float*)d_in[3];
    const float* Win  = (const float*)d_in[4];
    const float* bin  = (const float*)d_in[5];
    const float* Wu0  = (const float*)d_in[6];
    const float* bu0  = (const float*)d_in[7];
    const float* Wr0  = (const float*)d_in[8];
    const float* br0  = (const float*)d_in[9];
    const float* Wc0  = (const float*)d_in[10];
    const float* bc0  = (const float*)d_in[11];
    const float* Wu1  = (const float*)d_in[12];
    const float* bu1  = (const float*)d_in[13];
    const float* Wr1  = (const float*)d_in[14];
    const float* br1  = (const float*)d_in[15];
    const float* Wc1  = (const float*)d_in[16];
    const float* bc1  = (const float*)d_in[17];
    const float* Wout = (const float*)d_in[18];
    const float* bout = (const float*)d_in[19];

    const size_t S = (size_t)BB * HIDD;      // 65536 floats
    float* ws = (float*)d_ws;
    float* h0b[2] = {ws,         ws + S};
    float* h1b[2] = {ws + 2 * S, ws + 3 * S};
    float* gu0  = ws + 4 * S;
    float* grh0 = ws + 5 * S;
    float* gu1  = ws + 6 * S;
    float* grh1 = ws + 7 * S;
    // gu0..grh1 (4x 128*512) double as the h0 partial buffer pre-loop
    unsigned short* s1bf = (unsigned short*)(ws + 8 * S);   // TT*128*512 bf16
    unsigned short* wT   = s1bf + (size_t)TT * BB * HIDD;   // 10000*512 bf16

    float* out = (float*)d_out;
    float* outS = out + (size_t)TT * BB * VOCAB;            // [2][128][512]

    k_wT<<<dim3(313, 16), 256, 0, stream>>>(Wout, wT);
    k_h0p<<<dim3(8, 64, 4), 256, 0, stream>>>(vgg, Win, gu0);
    k_h0f<<<dim3(64), 256, 0, stream>>>(gu0, bin, h0b[1], h1b[1]);

    // Layer-pipelined recurrence: iteration i = L0 step t0=i and L1 step t1=i-1.
    for (int i = 0; i <= TT; ++i) {
        int doL0 = (i < TT), doL1 = (i >= 1);
        const float* h0p_ = h0b[(i + 1) & 1];   // h0_{i-1}
        float*       h0c_ = h0b[i & 1];         // h0_i
        const float* h1p_ = h1b[i & 1];         // h1_{i-2}
        float*       h1c_ = h1b[(i + 1) & 1];   // h1_{i-1}

        k_gates<<<dim3(512), 512, 0, stream>>>(h0p_, h1p_, toks, emb, i,
                                               Wu0, bu0, Wr0, br0,
                                               Wu1, bu1, Wr1, br1,
                                               gu0, grh0, gu1, grh1,
                                               doL0, doL1);
        k_cand<<<dim3(256), 512, 0, stream>>>(h0p_, h1p_, h0c_, h1c_,
                                              toks, emb, i, i - 1,
                                              Wc0, bc0, Wc1, bc1,
                                              gu0, grh0, gu1, grh1,
                                              s1bf, outS, doL0, doL1);
    }

    k_logits<<<dim3(2000), 256, 0, stream>>>(s1bf, wT, bout, out);
}